// Round 12
// baseline (563.343 us; speedup 1.0000x reference)
//
#include <hip/hip_runtime.h>

#define IN_F 512
#define OUT_F 32

typedef __attribute__((ext_vector_type(8))) short bf16x8;
typedef __attribute__((ext_vector_type(4))) float f32x4;

// round-to-nearest-even f32 -> bf16 bits
__device__ __forceinline__ unsigned short f2bf(float f) {
    unsigned u = __float_as_uint(f);
    return (unsigned short)((u + 0x7fffu + ((u >> 16) & 1u)) >> 16);
}
__device__ __forceinline__ float bf2f(unsigned short b) {
    return __uint_as_float(((unsigned)b) << 16);
}

// ---------------------------------------------------------------------------
// MFMA GEMM (round-7, measured-good: passed, gemm dropped out of top-5).
// x split into bf16 hi+lo (Dekker), W single bf16; h = x @ W + bias.
// ---------------------------------------------------------------------------
#define AHI 0
#define ALO 8192
#define WTO 16384

__global__ __launch_bounds__(256) void gemm_kernel(
    const float* __restrict__ x, const float* __restrict__ W,
    const float* __restrict__ bias, float* __restrict__ h, int n_rows) {
    __shared__ char lds[49152];

    const int tid = threadIdx.x;
    const int rowbase = blockIdx.x * 64;
    const int lane = tid & 63;
    const int wid = tid >> 6;

    for (int i = tid; i < IN_F * OUT_F; i += 256) {
        const int k = i >> 5, c = i & 31;
        const unsigned off =
            ((unsigned)(c * 1024 + k * 2)) ^ (unsigned)((c & 7) << 4);
        *(unsigned short*)(lds + WTO + off) = f2bf(W[i]);
    }

    f32x4 acc0 = {0.f, 0.f, 0.f, 0.f};
    f32x4 acc1 = {0.f, 0.f, 0.f, 0.f};

    const int sr = tid >> 4;
    const int sc = tid & 15;

    for (int kc = 0; kc < IN_F; kc += 64) {
#pragma unroll
        for (int p = 0; p < 4; ++p) {
            const int r = p * 16 + sr;
            const int grow = rowbase + r;
            float4 v = make_float4(0.f, 0.f, 0.f, 0.f);
            if (grow < n_rows)
                v = *(const float4*)(x + (size_t)grow * IN_F + kc + sc * 4);
            const unsigned short h0 = f2bf(v.x), h1 = f2bf(v.y);
            const unsigned short h2 = f2bf(v.z), h3 = f2bf(v.w);
            const float l0 = v.x - bf2f(h0), l1 = v.y - bf2f(h1);
            const float l2 = v.z - bf2f(h2), l3 = v.w - bf2f(h3);
            const unsigned hiA = (unsigned)h0 | ((unsigned)h1 << 16);
            const unsigned hiB = (unsigned)h2 | ((unsigned)h3 << 16);
            const unsigned loA = (unsigned)f2bf(l0) | ((unsigned)f2bf(l1) << 16);
            const unsigned loB = (unsigned)f2bf(l2) | ((unsigned)f2bf(l3) << 16);
            const unsigned off =
                ((unsigned)(r * 128 + sc * 8)) ^ (unsigned)((r & 7) << 4);
            *(uint2*)(lds + AHI + off) = make_uint2(hiA, hiB);
            *(uint2*)(lds + ALO + off) = make_uint2(loA, loB);
        }
        __syncthreads();

#pragma unroll
        for (int ks = 0; ks < 2; ++ks) {
            const int arow = wid * 16 + (lane & 15);
            const int akb = ks * 32 + (lane >> 4) * 8;
            const unsigned aoff =
                ((unsigned)(arow * 128 + akb * 2)) ^ (unsigned)((arow & 7) << 4);
            const bf16x8 ahi = *(const bf16x8*)(lds + AHI + aoff);
            const bf16x8 alo = *(const bf16x8*)(lds + ALO + aoff);
            const int kgl = kc + akb;
            const int c0 = lane & 15;
            const unsigned b0off =
                ((unsigned)(c0 * 1024 + kgl * 2)) ^ (unsigned)((c0 & 7) << 4);
            const unsigned b1off =
                ((unsigned)((c0 + 16) * 1024 + kgl * 2)) ^
                (unsigned)((c0 & 7) << 4);
            const bf16x8 b0 = *(const bf16x8*)(lds + WTO + b0off);
            const bf16x8 b1 = *(const bf16x8*)(lds + WTO + b1off);
            acc0 = __builtin_amdgcn_mfma_f32_16x16x32_bf16(ahi, b0, acc0, 0, 0, 0);
            acc0 = __builtin_amdgcn_mfma_f32_16x16x32_bf16(alo, b0, acc0, 0, 0, 0);
            acc1 = __builtin_amdgcn_mfma_f32_16x16x32_bf16(ahi, b1, acc1, 0, 0, 0);
            acc1 = __builtin_amdgcn_mfma_f32_16x16x32_bf16(alo, b1, acc1, 0, 0, 0);
        }
        __syncthreads();
    }

    const int col = lane & 15;
    const float bv0 = bias[col];
    const float bv1 = bias[col + 16];
#pragma unroll
    for (int r = 0; r < 4; ++r) {
        const int row = rowbase + wid * 16 + (lane >> 4) * 4 + r;
        if (row < n_rows) {
            h[(size_t)row * OUT_F + col] = acc0[r] + bv0;
            h[(size_t)row * OUT_F + col + 16] = acc1[r] + bv1;
        }
    }
}

// ---------------------------------------------------------------------------
// CSR v2: replace 51.2M fp32 atomics (measured wall: ~300 G/s, 171 us) with
// 3.2M int atomics + L2-resident streams. v2 fixes vs round-3: (src,w)
// packed into ONE uint2 (1.6M 8B scattered writes into a 12.8MB L2-resident
// array, ~16 writes/line amortized), gather writes out directly (no memset,
// no atomics anywhere in the fp32 path).
// ---------------------------------------------------------------------------
__global__ __launch_bounds__(256) void hist_kernel(const int* __restrict__ ei,
                                                   int* __restrict__ deg,
                                                   int n_edges) {
    const int e = blockIdx.x * 256 + threadIdx.x;
    if (e < n_edges) atomicAdd(&deg[ei[e]], 1);
}

__global__ __launch_bounds__(256) void scan_sum(const int* __restrict__ deg,
                                                int* __restrict__ bsum, int n) {
    __shared__ int sm[256];
    const int t = threadIdx.x;
    const int base = blockIdx.x * 1024;
    int s = 0;
    for (int j = 0; j < 4; ++j) {
        const int idx = base + t + j * 256;
        if (idx < n) s += deg[idx];
    }
    sm[t] = s;
    __syncthreads();
    for (int st = 128; st > 0; st >>= 1) {
        if (t < st) sm[t] += sm[t + st];
        __syncthreads();
    }
    if (t == 0) bsum[blockIdx.x] = sm[0];
}

__global__ __launch_bounds__(128) void scan_top(int* __restrict__ bsum, int nb,
                                                int* __restrict__ offsets,
                                                int n_nodes, int n_edges) {
    __shared__ int sm[128];
    const int t = threadIdx.x;
    sm[t] = (t < nb) ? bsum[t] : 0;
    __syncthreads();
    for (int st = 1; st < 128; st <<= 1) {
        const int add = (t >= st) ? sm[t - st] : 0;
        __syncthreads();
        sm[t] += add;
        __syncthreads();
    }
    if (t < nb) bsum[t] = (t == 0) ? 0 : sm[t - 1];
    if (t == 0) offsets[n_nodes] = n_edges;
}

__global__ __launch_bounds__(256) void scan_final(int* __restrict__ deg,
                                                  int* __restrict__ cursor,
                                                  const int* __restrict__ bsum,
                                                  int n) {
    __shared__ int sm[256];
    const int t = threadIdx.x;
    const int base = blockIdx.x * 1024;
    int v[4];
    int loc = 0;
#pragma unroll
    for (int j = 0; j < 4; ++j) {
        const int idx = base + t * 4 + j;
        v[j] = (idx < n) ? deg[idx] : 0;
        loc += v[j];
    }
    sm[t] = loc;
    __syncthreads();
    for (int st = 1; st < 256; st <<= 1) {
        const int add = (t >= st) ? sm[t - st] : 0;
        __syncthreads();
        sm[t] += add;
        __syncthreads();
    }
    int run = bsum[blockIdx.x] + ((t == 0) ? 0 : sm[t - 1]);
#pragma unroll
    for (int j = 0; j < 4; ++j) {
        const int idx = base + t * 4 + j;
        if (idx < n) {
            deg[idx] = run;
            cursor[idx] = run;
            run += v[j];
        }
    }
}

__global__ __launch_bounds__(256) void scatter_kernel(
    const int* __restrict__ ei, const float* __restrict__ ew,
    int* __restrict__ cursor, uint2* __restrict__ packed, int n_edges) {
    const int e = blockIdx.x * 256 + threadIdx.x;
    if (e < n_edges) {
        const int d = ei[e];
        const int s = ei[n_edges + e];
        const float w = ew[e];
        const int slot = atomicAdd(&cursor[d], 1);
        packed[slot] = make_uint2((unsigned)s, __float_as_uint(w));
    }
}

// 16 lanes per node; lane fp accumulates features {2fp,2fp+1}. Zero atomics;
// writes every node (deg==0 -> zeros), so no d_out memset needed.
__global__ __launch_bounds__(256) void gather_kernel(
    const int* __restrict__ offsets, const uint2* __restrict__ packed,
    const float* __restrict__ h, float* __restrict__ out, int n_nodes) {
    const int g = blockIdx.x * 16 + (threadIdx.x >> 4);
    const int fp = threadIdx.x & 15;
    if (g >= n_nodes) return;
    const int beg = offsets[g];
    const int end = offsets[g + 1];
    float ax = 0.f, ay = 0.f;
#pragma unroll 4
    for (int j = beg; j < end; ++j) {
        const uint2 p = packed[j];
        const float w = __uint_as_float(p.y);
        const float2 hv =
            *(const float2*)(h + (size_t)p.x * OUT_F + fp * 2);
        ax = fmaf(w, hv.x, ax);
        ay = fmaf(w, hv.y, ay);
    }
    float2 o;
    o.x = ax;
    o.y = ay;
    *(float2*)(out + (size_t)g * OUT_F + fp * 2) = o;
}

// fallback (measured 171us): thread per (edge, feature) fp32 atomics
__global__ __launch_bounds__(256) void edge_atomic_kernel(
    const int* __restrict__ ei, const float* __restrict__ ew,
    const float* __restrict__ h, float* __restrict__ out, int n_edges) {
    const long long idx = (long long)blockIdx.x * 256 + threadIdx.x;
    const int e = (int)(idx >> 5);
    const int f = (int)(idx & 31);
    if (e < n_edges) {
        const int d = ei[e];
        const int s = ei[n_edges + e];
        const float w = ew[e];
        atomicAdd(out + (size_t)d * OUT_F + f, w * h[(size_t)s * OUT_F + f]);
    }
}

extern "C" void kernel_launch(void* const* d_in, const int* in_sizes, int n_in,
                              void* d_out, int out_size, void* d_ws,
                              size_t ws_size, hipStream_t stream) {
    const float* x = (const float*)d_in[0];
    const float* W = (const float*)d_in[1];
    const float* bias = (const float*)d_in[2];
    const float* ew = (const float*)d_in[3];
    const int* ei = (const int*)d_in[4];
    float* out = (float*)d_out;

    const int n_nodes = in_sizes[0] / IN_F;
    const int n_edges = in_sizes[3];

    // workspace layout
    char* ws = (char*)d_ws;
    const size_t sz_h = (size_t)n_nodes * OUT_F * sizeof(float);
    const size_t off_deg = (sz_h + 63) & ~(size_t)63;
    const size_t sz_deg = (size_t)(n_nodes + 1) * sizeof(int);
    const size_t off_cur = (off_deg + sz_deg + 63) & ~(size_t)63;
    const size_t sz_cur = (size_t)n_nodes * sizeof(int);
    const size_t off_pk = (off_cur + sz_cur + 63) & ~(size_t)63;
    const size_t sz_pk = (size_t)n_edges * sizeof(uint2);
    const size_t off_bsum = (off_pk + sz_pk + 63) & ~(size_t)63;
    const size_t required = off_bsum + 512 * sizeof(int);

    float* h = (float*)ws;

    gemm_kernel<<<(n_nodes + 63) / 64, 256, 0, stream>>>(x, W, bias, h,
                                                         n_nodes);

    const int nb = (n_nodes + 1023) / 1024;  // 98
    if (ws_size >= required && nb <= 128) {
        int* deg = (int*)(ws + off_deg);  // -> offsets after scan
        int* cursor = (int*)(ws + off_cur);
        uint2* packed = (uint2*)(ws + off_pk);
        int* bsum = (int*)(ws + off_bsum);

        (void)hipMemsetAsync(deg, 0, sz_deg, stream);
        hist_kernel<<<(n_edges + 255) / 256, 256, 0, stream>>>(ei, deg,
                                                               n_edges);
        scan_sum<<<nb, 256, 0, stream>>>(deg, bsum, n_nodes);
        scan_top<<<1, 128, 0, stream>>>(bsum, nb, deg, n_nodes, n_edges);
        scan_final<<<nb, 256, 0, stream>>>(deg, cursor, bsum, n_nodes);
        scatter_kernel<<<(n_edges + 255) / 256, 256, 0, stream>>>(
            ei, ew, cursor, packed, n_edges);
        gather_kernel<<<(n_nodes + 15) / 16, 256, 0, stream>>>(deg, packed, h,
                                                               out, n_nodes);
    } else {
        (void)hipMemsetAsync(d_out, 0, (size_t)out_size * sizeof(float),
                             stream);
        const long long work = (long long)n_edges * OUT_F;
        edge_atomic_kernel<<<(int)((work + 255) / 256), 256, 0, stream>>>(
            ei, ew, h, out, n_edges);
    }
}